// Round 1
// baseline (957.503 us; speedup 1.0000x reference)
//
#include <hip/hip_runtime.h>
#include <stdint.h>

typedef unsigned short u16;
typedef unsigned int   u32;

#define RR 31
#define WW 512
#define HH 512
#define BB 4
#define CC 32
#define EPSW 1e-3f

__device__ __forceinline__ int reflect512(int i) {
    i = (i < 0) ? -i : i;
    return (i >= WW) ? (2*WW - 2 - i) : i;
}

__device__ __forceinline__ u16 f2bf(float f) {
    u32 u = __float_as_uint(f);
    u32 r = (u + 0x7fffu + ((u >> 16) & 1u)) >> 16;
    return (u16)r;
}

union F4 { float4 v; float f[4]; };

__device__ __forceinline__ void unpack4(uint2 v, float* o) {
    union { u32 u; float f; } a, b, c, d;
    a.u = v.x << 16; b.u = v.x & 0xffff0000u;
    c.u = v.y << 16; d.u = v.y & 0xffff0000u;
    o[0] = a.f; o[1] = b.f; o[2] = c.f; o[3] = d.f;
}

// ---------------- horizontal pass: x (f32) -> o1,o2 (bf16) ----------------
// grid (8 cchunks, 512 h, 4 b), block 128. Thread owns 4 consecutive w.
__global__ __launch_bounds__(128)
void hpass(const float* __restrict__ x, const float* __restrict__ sig,
           u16* __restrict__ o1, u16* __restrict__ o2)
{
    __shared__ float xs[4][576];   // 4 ch, padded row: i -> w = i-32 (reflect)
    const int t  = threadIdx.x;
    const int c0 = blockIdx.x * 4;
    const int h  = blockIdx.y;
    const int b  = blockIdx.z;

    #pragma unroll
    for (int c = 0; c < 4; ++c) {
        const float* src = x + ((size_t)((b*CC + c0 + c)*HH + h))*WW;
        for (int i = t; i < 576; i += 128)
            xs[c][i] = src[reflect512(i - 32)];
    }
    __syncthreads();

    const int w0 = t * 4;
    F4 sgq; sgq.v = *(const float4*)(sig + ((size_t)(b*HH + h))*WW + w0);

    float m1[4], q21[4], m2[4], q22[4], wv1[4], wv2[4], S1[4], S2[4];
    #pragma unroll
    for (int p = 0; p < 4; ++p) {
        float s   = sgq.f[p];
        float tt1 = -0.5f / (s*s);
        m1[p] = __expf(tt1);              q21[p] = m1[p]*m1[p];
        float tt2 = tt1 * (1.0f/2.56f);   // sigma2 = 1.6*sigma
        m2[p] = __expf(tt2);              q22[p] = m2[p]*m2[p];
        wv1[p] = 1.f; wv2[p] = 1.f; S1[p] = 0.f; S2[p] = 0.f;
    }

    float a1[4][4], a2[4][4];  // [c][p], unnormalized accumulators
    F4 Lhi[4], Rlo[4];         // carried quads per channel
    #pragma unroll
    for (int c = 0; c < 4; ++c) {
        F4 Cq; Cq.v = *(const float4*)&xs[c][32 + w0];
        #pragma unroll
        for (int p = 0; p < 4; ++p) { a1[c][p] = Cq.f[p]; a2[c][p] = Cq.f[p]; }
        Lhi[c] = Cq; Rlo[c] = Cq;
    }

    #pragma unroll
    for (int kb = 0; kb < 8; ++kb) {     // taps k = 4kb+1 .. 4kb+4 (k=32 zero-weighted)
        float tw1[4][4], tw2[4][4];      // [j][p]
        #pragma unroll
        for (int j = 0; j < 4; ++j)
            #pragma unroll
            for (int p = 0; p < 4; ++p) {
                wv1[p] *= m1[p]; m1[p] *= q21[p];
                wv2[p] *= m2[p]; m2[p] *= q22[p];
                float ta = (wv1[p] >= EPSW) ? wv1[p] : 0.f;
                float tb = (wv2[p] >= EPSW) ? wv2[p] : 0.f;
                if (j == 3 && kb == 7) { ta = 0.f; tb = 0.f; }   // k=32 pad tap
                tw1[j][p] = ta; S1[p] += ta;
                tw2[j][p] = tb; S2[p] += tb;
            }
        const int li = 32 + w0 - 4 - 4*kb;
        const int ri = 32 + w0 + 4 + 4*kb;
        #pragma unroll
        for (int c = 0; c < 4; ++c) {
            F4 Llo, Rhi;
            Llo.v = *(const float4*)&xs[c][li];
            Rhi.v = *(const float4*)&xs[c][ri];
            #pragma unroll
            for (int j = 0; j < 4; ++j)
                #pragma unroll
                for (int p = 0; p < 4; ++p) {
                    float l = (p - j + 3 < 4) ? Llo.f[p - j + 3] : Lhi[c].f[p - j - 1];
                    float r = (p + j + 1 < 4) ? Rlo[c].f[p + j + 1] : Rhi.f[p + j - 3];
                    float sv = l + r;                         // shared across gaussians
                    a1[c][p] = fmaf(tw1[j][p], sv, a1[c][p]);
                    a2[c][p] = fmaf(tw2[j][p], sv, a2[c][p]);
                }
            Lhi[c] = Llo; Rlo[c] = Rhi;
        }
    }

    float n1[4], n2[4];
    #pragma unroll
    for (int p = 0; p < 4; ++p) {
        n1[p] = 1.0f / (1.0f + 2.0f*S1[p] + 1e-8f);
        n2[p] = 1.0f / (1.0f + 2.0f*S2[p] + 1e-8f);
    }
    #pragma unroll
    for (int c = 0; c < 4; ++c) {
        union { u16 u[4]; uint2 q; } pk1, pk2;
        #pragma unroll
        for (int p = 0; p < 4; ++p) {
            pk1.u[p] = f2bf(a1[c][p]*n1[p]);
            pk2.u[p] = f2bf(a2[c][p]*n2[p]);
        }
        size_t base = ((size_t)((b*CC + c0 + c)*HH + h))*WW + w0;
        *(uint2*)(o1 + base) = pk1.q;
        *(uint2*)(o2 + base) = pk2.q;
    }
}

// ---------------- vertical pass: o1,o2 (bf16) -> out (f32, diff) ----------------
// grid (16 wtiles, 8 htiles, 32 = b*8+cchunk), block 512 = 32 w x 16 hquads.
// LDS tile per chunk: [4c][32w][128 h-contig bf16], XOR quad-swizzled. 64KB total.
__global__ __launch_bounds__(512)
void vpass(const u16* __restrict__ i1, const u16* __restrict__ i2,
           const float* __restrict__ sig, float* __restrict__ out)
{
    __shared__ u16 ls1[4*32*128];
    __shared__ u16 ls2[4*32*128];
    const int t   = threadIdx.x;
    const int w   = t & 31;
    const int hq  = t >> 5;
    const int wg0 = blockIdx.x * 32;
    const int h0  = blockIdx.y * 64;
    const int bz  = blockIdx.z;
    const int b   = bz >> 3;
    const int c0  = (bz & 7) * 4;

    #pragma unroll
    for (int c = 0; c < 4; ++c) {
        const u16* s1p = i1 + ((size_t)((b*CC + c0 + c)*HH))*WW;
        const u16* s2p = i2 + ((size_t)((b*CC + c0 + c)*HH))*WW;
        for (int idx = t; idx < 4096; idx += 512) {
            int r  = idx >> 5, wl = idx & 31;
            int hh = reflect512(h0 - 32 + r);            // rows h0-32 .. h0+95
            int gi = hh*WW + wg0 + wl;
            int li = ((c*32 + wl) << 7) + (((r >> 2) ^ ((wl & 7) << 1)) << 2) + (r & 3);
            ls1[li] = s1p[gi];
            ls2[li] = s2p[gi];
        }
    }
    __syncthreads();

    float m1[4], q21[4], m2[4], q22[4], wv1[4], wv2[4], S1[4], S2[4];
    #pragma unroll
    for (int p = 0; p < 4; ++p) {
        float s   = sig[((size_t)(b*HH + h0 + 4*hq + p))*WW + wg0 + w];
        float tt1 = -0.5f / (s*s);
        m1[p] = __expf(tt1);              q21[p] = m1[p]*m1[p];
        float tt2 = tt1 * (1.0f/2.56f);
        m2[p] = __expf(tt2);              q22[p] = m2[p]*m2[p];
        wv1[p] = 1.f; wv2[p] = 1.f; S1[p] = 0.f; S2[p] = 0.f;
    }

    float a1[4][4], a2[4][4];
    uint2 C1L[4], C1R[4], C2L[4], C2R[4];
    const int qc = 8 + hq;                 // center quad (rows 32+4hq..)
    #pragma unroll
    for (int c = 0; c < 4; ++c) {
        int base = ((c*32 + w) << 7) + ((qc ^ ((w & 7) << 1)) << 2);
        uint2 v1 = *(const uint2*)&ls1[base];
        uint2 v2 = *(const uint2*)&ls2[base];
        float f1[4], f2[4];
        unpack4(v1, f1); unpack4(v2, f2);
        #pragma unroll
        for (int p = 0; p < 4; ++p) { a1[c][p] = f1[p]; a2[c][p] = f2[p]; }
        C1L[c] = v1; C1R[c] = v1;
        C2L[c] = v2; C2R[c] = v2;
    }

    #pragma unroll 1
    for (int kb = 0; kb < 8; ++kb) {
        float tw1[4][4], tw2[4][4];
        #pragma unroll
        for (int j = 0; j < 4; ++j)
            #pragma unroll
            for (int p = 0; p < 4; ++p) {
                wv1[p] *= m1[p]; m1[p] *= q21[p];
                wv2[p] *= m2[p]; m2[p] *= q22[p];
                float ta = (wv1[p] >= EPSW) ? wv1[p] : 0.f;
                float tb = (wv2[p] >= EPSW) ? wv2[p] : 0.f;
                if (j == 3) { ta = (kb == 7) ? 0.f : ta; tb = (kb == 7) ? 0.f : tb; }
                tw1[j][p] = ta; S1[p] += ta;
                tw2[j][p] = tb; S2[p] += tb;
            }
        const int ql = 7 + hq - kb;
        const int qr = 9 + hq + kb;
        #pragma unroll
        for (int c = 0; c < 4; ++c) {
            int rowb = (c*32 + w) << 7;
            int bl = rowb + ((ql ^ ((w & 7) << 1)) << 2);
            int br = rowb + ((qr ^ ((w & 7) << 1)) << 2);
            uint2 L1 = *(const uint2*)&ls1[bl];
            uint2 R1 = *(const uint2*)&ls1[br];
            uint2 L2 = *(const uint2*)&ls2[bl];
            uint2 R2 = *(const uint2*)&ls2[br];
            float l1v[8], r1v[8], l2v[8], r2v[8];
            unpack4(L1, &l1v[0]); unpack4(C1L[c], &l1v[4]);
            unpack4(C1R[c], &r1v[0]); unpack4(R1, &r1v[4]);
            unpack4(L2, &l2v[0]); unpack4(C2L[c], &l2v[4]);
            unpack4(C2R[c], &r2v[0]); unpack4(R2, &r2v[4]);
            #pragma unroll
            for (int j = 0; j < 4; ++j)
                #pragma unroll
                for (int p = 0; p < 4; ++p) {
                    float sA = l1v[p - j + 3] + r1v[p + j + 1];
                    a1[c][p] = fmaf(tw1[j][p], sA, a1[c][p]);
                    float sB = l2v[p - j + 3] + r2v[p + j + 1];
                    a2[c][p] = fmaf(tw2[j][p], sB, a2[c][p]);
                }
            C1L[c] = L1; C1R[c] = R1; C2L[c] = L2; C2R[c] = R2;
        }
    }

    float n1[4], n2[4];
    #pragma unroll
    for (int p = 0; p < 4; ++p) {
        n1[p] = 1.0f / (1.0f + 2.0f*S1[p] + 1e-8f);
        n2[p] = 1.0f / (1.0f + 2.0f*S2[p] + 1e-8f);
    }
    #pragma unroll
    for (int c = 0; c < 4; ++c)
        #pragma unroll
        for (int p = 0; p < 4; ++p) {
            size_t o = ((size_t)((b*CC + c0 + c)*HH + h0 + 4*hq + p))*WW + wg0 + w;
            out[o] = a2[c][p]*n2[p] - a1[c][p]*n1[p];
        }
}

extern "C" void kernel_launch(void* const* d_in, const int* in_sizes, int n_in,
                              void* d_out, int out_size, void* d_ws, size_t ws_size,
                              hipStream_t stream) {
    const float* x   = (const float*)d_in[0];
    const float* sig = (const float*)d_in[1];
    float* out = (float*)d_out;

    const size_t n = (size_t)BB*CC*HH*WW;          // 33.55M elems
    if (ws_size < n * 2 * sizeof(u16)) return;      // need 134MB scratch (bf16 x2)
    u16* o1 = (u16*)d_ws;
    u16* o2 = o1 + n;

    hpass<<<dim3(8, 512, 4), 128, 0, stream>>>(x, sig, o1, o2);
    vpass<<<dim3(16, 8, 32), 512, 0, stream>>>(o1, o2, sig, out);
}

// Round 2
// 434.809 us; speedup vs baseline: 2.2021x; 2.2021x over previous
//
#include <hip/hip_runtime.h>
#include <stdint.h>

typedef unsigned short u16;
typedef unsigned int   u32;

#define RR 31
#define WW 512
#define HH 512
#define BB 4
#define CC 32
#define EPSW 1e-3f

__device__ __forceinline__ int reflect512(int i) {
    i = (i < 0) ? -i : i;
    return (i >= WW) ? (2*WW - 2 - i) : i;
}

__device__ __forceinline__ u16 f2bf(float f) {
    u32 u = __float_as_uint(f);
    u32 r = (u + 0x7fffu + ((u >> 16) & 1u)) >> 16;
    return (u16)r;
}

__device__ __forceinline__ void unpack4(uint2 v, float* o) {
    union { u32 u; float f; } a, b, c, d;
    a.u = v.x << 16; b.u = v.x & 0xffff0000u;
    c.u = v.y << 16; d.u = v.y & 0xffff0000u;
    o[0] = a.f; o[1] = b.f; o[2] = c.f; o[3] = d.f;
}

// ---------------- horizontal pass: x (f32) -> ws (u32: {g1 bf16, g2 bf16}) ----
// grid (8 cchunks, 512 h, 4 b), block 256. Thread owns 2 consecutive w, 4 ch,
// both gaussians (shares the l+r symmetric sums).
__global__ __launch_bounds__(256, 4)
void hpass(const float* __restrict__ x, const float* __restrict__ sig,
           u32* __restrict__ ws)
{
    __shared__ float xs[4][576];   // i -> w = i-32 (reflect)
    const int t  = threadIdx.x;
    const int c0 = blockIdx.x * 4;
    const int h  = blockIdx.y;
    const int b  = blockIdx.z;

    #pragma unroll
    for (int c = 0; c < 4; ++c) {
        const float* src = x + ((size_t)((b*CC + c0 + c)*HH + h))*WW;
        for (int i = t; i < 576; i += 256)
            xs[c][i] = src[reflect512(i - 32)];
    }
    __syncthreads();

    const int w0 = t * 2;
    float2 sg = *(const float2*)(sig + ((size_t)(b*HH + h))*WW + w0);

    float m1[2], q1[2], wv1[2], S1[2], m2[2], q2[2], wv2[2], S2[2];
    #pragma unroll
    for (int p = 0; p < 2; ++p) {
        float s   = p ? sg.y : sg.x;
        float tt1 = -0.5f / (s*s);
        m1[p] = __expf(tt1);             q1[p] = m1[p]*m1[p];
        float tt2 = tt1 * (1.0f/2.56f);  // sigma2 = 1.6*sigma
        m2[p] = __expf(tt2);             q2[p] = m2[p]*m2[p];
        wv1[p] = 1.f; wv2[p] = 1.f; S1[p] = 0.f; S2[p] = 0.f;
    }

    float a1[4][2], a2[4][2];
    float2 Lhi[4], Rlo[4];
    #pragma unroll
    for (int c = 0; c < 4; ++c) {
        float2 Cq = *(const float2*)&xs[c][32 + w0];
        a1[c][0] = Cq.x; a1[c][1] = Cq.y;
        a2[c][0] = Cq.x; a2[c][1] = Cq.y;
        Lhi[c] = Cq; Rlo[c] = Cq;
    }

    #pragma unroll 1
    for (int kb = 0; kb < 15; ++kb) {      // taps k = 2kb+1, 2kb+2  (k=1..30)
        float tw1[2][2], tw2[2][2];        // [j][p]
        #pragma unroll
        for (int j = 0; j < 2; ++j)
            #pragma unroll
            for (int p = 0; p < 2; ++p) {
                wv1[p] *= m1[p]; m1[p] *= q1[p];
                float ta = (wv1[p] >= EPSW) ? wv1[p] : 0.f;
                tw1[j][p] = ta; S1[p] += ta;
                wv2[p] *= m2[p]; m2[p] *= q2[p];
                float tb = (wv2[p] >= EPSW) ? wv2[p] : 0.f;
                tw2[j][p] = tb; S2[p] += tb;
            }
        const int li = 32 + w0 - 2 - 2*kb;
        const int ri = 32 + w0 + 2 + 2*kb;
        #pragma unroll
        for (int c = 0; c < 4; ++c) {
            float2 Llo = *(const float2*)&xs[c][li];
            float2 Rhi = *(const float2*)&xs[c][ri];
            float s00 = Llo.y    + Rlo[c].y;   // p0, j0  (k=2kb+1)
            float s01 = Llo.x    + Rhi.x;      // p0, j1  (k=2kb+2)
            float s10 = Lhi[c].x + Rhi.x;      // p1, j0
            float s11 = Llo.y    + Rhi.y;      // p1, j1
            a1[c][0] = fmaf(tw1[0][0], s00, a1[c][0]);
            a1[c][0] = fmaf(tw1[1][0], s01, a1[c][0]);
            a1[c][1] = fmaf(tw1[0][1], s10, a1[c][1]);
            a1[c][1] = fmaf(tw1[1][1], s11, a1[c][1]);
            a2[c][0] = fmaf(tw2[0][0], s00, a2[c][0]);
            a2[c][0] = fmaf(tw2[1][0], s01, a2[c][0]);
            a2[c][1] = fmaf(tw2[0][1], s10, a2[c][1]);
            a2[c][1] = fmaf(tw2[1][1], s11, a2[c][1]);
            Lhi[c] = Llo; Rlo[c] = Rhi;
        }
    }

    {   // epilogue tap k = 31
        float t1e[2], t2e[2];
        #pragma unroll
        for (int p = 0; p < 2; ++p) {
            wv1[p] *= m1[p];
            float ta = (wv1[p] >= EPSW) ? wv1[p] : 0.f;
            t1e[p] = ta; S1[p] += ta;
            wv2[p] *= m2[p];
            float tb = (wv2[p] >= EPSW) ? wv2[p] : 0.f;
            t2e[p] = tb; S2[p] += tb;
        }
        const int li = 32 + w0 - 32;
        const int ri = 32 + w0 + 32;
        #pragma unroll
        for (int c = 0; c < 4; ++c) {
            float2 Lle = *(const float2*)&xs[c][li];
            float2 Rre = *(const float2*)&xs[c][ri];
            float s0 = Lle.y    + Rlo[c].y;    // p0: w0-31, w0+31
            float s1 = Lhi[c].x + Rre.x;       // p1: w0-30, w0+32
            a1[c][0] = fmaf(t1e[0], s0, a1[c][0]);
            a1[c][1] = fmaf(t1e[1], s1, a1[c][1]);
            a2[c][0] = fmaf(t2e[0], s0, a2[c][0]);
            a2[c][1] = fmaf(t2e[1], s1, a2[c][1]);
        }
    }

    float n1[2], n2[2];
    #pragma unroll
    for (int p = 0; p < 2; ++p) {
        n1[p] = 1.0f / (1.0f + 2.0f*S1[p] + 1e-8f);
        n2[p] = 1.0f / (1.0f + 2.0f*S2[p] + 1e-8f);
    }
    #pragma unroll
    for (int c = 0; c < 4; ++c) {
        uint2 pk;
        pk.x = (u32)f2bf(a1[c][0]*n1[0]) | ((u32)f2bf(a2[c][0]*n2[0]) << 16);
        pk.y = (u32)f2bf(a1[c][1]*n1[1]) | ((u32)f2bf(a2[c][1]*n2[1]) << 16);
        size_t base = ((size_t)((b*CC + c0 + c)*HH + h))*WW + w0;
        *(uint2*)(ws + base) = pk;
    }
}

// ---------------- vertical pass: ws -> out (f32, diff) ----------------------
// grid (16 wtiles, 8 htiles, 32 = b*8+cchunk), block 1024 = 2 g-halves of
// (32w x 16 h-quads). Each thread: 4 ch x 4 h x ONE gaussian. g2 subtracts
// g1's result via LDS exchange. LDS tap layout [g][c][w][q^(w&15)][4] bf16.
__global__ __launch_bounds__(1024, 4)
void vpass(const u32* __restrict__ ws, const float* __restrict__ sig,
           float* __restrict__ out)
{
    __shared__ __align__(16) u16 ls[2][4*32*32*4];   // 64 KB
    const int t   = threadIdx.x;
    const int w   = t & 31;
    const int hq  = (t >> 5) & 15;
    const int g   = t >> 9;
    const int wg0 = blockIdx.x * 32;
    const int h0  = blockIdx.y * 64;
    const int bz  = blockIdx.z;
    const int b   = bz >> 3;
    const int c0  = (bz & 7) * 4;

    #pragma unroll
    for (int c = 0; c < 4; ++c) {
        const u32* src = ws + ((size_t)((b*CC + c0 + c)*HH))*WW;
        #pragma unroll
        for (int it = 0; it < 4; ++it) {
            int idx = t + it*1024;
            int r = idx >> 5, wl = idx & 31;
            int hh = reflect512(h0 - 32 + r);          // rows h0-32 .. h0+95
            u32 v = src[hh*WW + wg0 + wl];
            int li = ((c*32 + wl) << 7) + (((r >> 2) ^ (wl & 15)) << 2) + (r & 3);
            ls[0][li] = (u16)v;
            ls[1][li] = (u16)(v >> 16);
        }
    }
    __syncthreads();

    float mm[4], qq[4], wv[4], S[4];
    #pragma unroll
    for (int p = 0; p < 4; ++p) {
        float s  = sig[((size_t)(b*HH + h0 + 4*hq + p))*WW + wg0 + w];
        float tt = -0.5f / (s*s);
        if (g) tt *= (1.0f/2.56f);
        mm[p] = __expf(tt); qq[p] = mm[p]*mm[p];
        wv[p] = 1.f; S[p] = 0.f;
    }

    const u16* lg = &ls[g][0];
    float a[4][4];
    uint2 CL[4], CR[4];
    const int qc = 8 + hq;
    #pragma unroll
    for (int c = 0; c < 4; ++c) {
        uint2 v = *(const uint2*)&lg[((c*32 + w) << 7) + ((qc ^ (w & 15)) << 2)];
        float f[4]; unpack4(v, f);
        #pragma unroll
        for (int p = 0; p < 4; ++p) a[c][p] = f[p];
        CL[c] = v; CR[c] = v;
    }

    #pragma unroll 1
    for (int kb = 0; kb < 8; ++kb) {       // taps k = 4kb+1 .. 4kb+4
        float tw[4][4];                    // [j][p]
        #pragma unroll
        for (int j = 0; j < 4; ++j)
            #pragma unroll
            for (int p = 0; p < 4; ++p) {
                wv[p] *= mm[p]; mm[p] *= qq[p];
                float ta = (wv[p] >= EPSW) ? wv[p] : 0.f;
                if (j == 3) ta = (kb == 7) ? 0.f : ta;   // k=32 pad tap
                tw[j][p] = ta; S[p] += ta;
            }
        const int ql = 7 + hq - kb;
        const int qr = 9 + hq + kb;
        #pragma unroll
        for (int c = 0; c < 4; ++c) {
            const int rowb = (c*32 + w) << 7;
            uint2 Lq = *(const uint2*)&lg[rowb + ((ql ^ (w & 15)) << 2)];
            uint2 Rq = *(const uint2*)&lg[rowb + ((qr ^ (w & 15)) << 2)];
            float lv[8], rv[8];
            unpack4(Lq, &lv[0]);    unpack4(CL[c], &lv[4]);
            unpack4(CR[c], &rv[0]); unpack4(Rq, &rv[4]);
            #pragma unroll
            for (int j = 0; j < 4; ++j)
                #pragma unroll
                for (int p = 0; p < 4; ++p) {
                    float s = lv[p - j + 3] + rv[p + j + 1];
                    a[c][p] = fmaf(tw[j][p], s, a[c][p]);
                }
            CL[c] = Lq; CR[c] = Rq;
        }
    }

    float n[4];
    #pragma unroll
    for (int p = 0; p < 4; ++p) n[p] = 1.0f / (1.0f + 2.0f*S[p] + 1e-8f);

    __syncthreads();                       // all tap reads done; reuse LDS
    float* xch = (float*)&ls[0][0];        // 32 KB exchange buffer
    if (g == 0) {
        #pragma unroll
        for (int c = 0; c < 4; ++c)
            #pragma unroll
            for (int p = 0; p < 4; ++p)
                xch[((c*16 + hq)*4 + p)*32 + w] = a[c][p]*n[p];
    }
    __syncthreads();
    if (g == 1) {
        #pragma unroll
        for (int c = 0; c < 4; ++c)
            #pragma unroll
            for (int p = 0; p < 4; ++p) {
                size_t o = ((size_t)((b*CC + c0 + c)*HH + h0 + 4*hq + p))*WW + wg0 + w;
                out[o] = a[c][p]*n[p] - xch[((c*16 + hq)*4 + p)*32 + w];
            }
    }
}

extern "C" void kernel_launch(void* const* d_in, const int* in_sizes, int n_in,
                              void* d_out, int out_size, void* d_ws, size_t ws_size,
                              hipStream_t stream) {
    const float* x   = (const float*)d_in[0];
    const float* sig = (const float*)d_in[1];
    float* out = (float*)d_out;

    const size_t n = (size_t)BB*CC*HH*WW;           // 33.55M px
    if (ws_size < n * sizeof(u32)) return;           // 134 MB interleaved bf16 pairs
    u32* ws = (u32*)d_ws;

    hpass<<<dim3(8, 512, 4), 256, 0, stream>>>(x, sig, ws);
    vpass<<<dim3(16, 8, 32), 1024, 0, stream>>>(ws, sig, out);
}